// Round 10
// baseline (417.509 us; speedup 1.0000x reference)
//
#include <hip/hip_runtime.h>
#include <hip/hip_bf16.h>

#define N_NODES 50000
#define N_EDGES 800000
#define D_IN 128
#define D_HID 512
#define D_OUT 128
#define CAT_DIM 640   // D_IN + D_HID
#define CAP 64        // per-node edge-bucket capacity (Poisson(16): P(>=64) ~ 1e-20)
#define HALF 25000    // trg-phase split point

typedef __attribute__((ext_vector_type(8))) short short8;
typedef __attribute__((ext_vector_type(4))) float floatx4;

__device__ __forceinline__ unsigned short f2bf(float f) {
    unsigned u = __float_as_uint(f);
    unsigned r = u + 0x7fffu + ((u >> 16) & 1u);   // RNE
    return (unsigned short)(r >> 16);
}

// convert 8 consecutive fp32 -> 8 bf16 (same bits as a pre-cast pass)
__device__ __forceinline__ void cvt8(const float* __restrict__ src, unsigned short* o) {
    float4 v0 = *(const float4*)src;
    float4 v1 = *(const float4*)(src + 4);
    o[0] = f2bf(v0.x); o[1] = f2bf(v0.y); o[2] = f2bf(v0.z); o[3] = f2bf(v0.w);
    o[4] = f2bf(v1.x); o[5] = f2bf(v1.y); o[6] = f2bf(v1.z); o[7] = f2bf(v1.w);
}

// ================= edge binning parameters =================================

#define NBKT 196         // ceil(50000/256)
#define BKT_SHIFT 8
#define CAPB 6144        // staging capacity/bucket (mean 4082, +32 sigma)
#define P1_CHUNK 4096
#define P1_BLOCKS 196    // ceil(800000/4096)

// ================= k0: fcwT transpose (the one gemm1 dependency, ~4 us) ====

#define K0_BLOCKS 256   // 128*512 / 256

__global__ __launch_bounds__(256)
void prep_fcw_kernel(const float* __restrict__ fcW, unsigned short* __restrict__ fcwT) {
    int idx = blockIdx.x * 256 + threadIdx.x;   // 128*512
    int k = idx >> 9;
    int n = idx & (D_HID - 1);
    fcwT[n * D_IN + k] = f2bf(fcW[idx]);
}

// ================= k1: pass-1 binning ∥ GEMM1 (A-once form) ∥ WT transpose =
// (R9 form, unchanged: front is gemm1-bound at ~95-115 us in every variant
// tried R5-R9; stop reshuffling. This round's delta is all in aggregate.)

#define S1_G1_BLOCKS 782    // ceil(50000/64)
#define S1_WT_BLOCKS 320    // 640*128 / 256
#define S1_BLOCKS (P1_BLOCKS + S1_G1_BLOCKS + S1_WT_BLOCKS)
#define G1_PAD 8
#define SM1_BYTES ((64 + 128) * (D_IN + G1_PAD) * 2)   // 52224

__global__ __launch_bounds__(256)
void sort_gemm1_kernel(const int* __restrict__ adj,
                       int* __restrict__ bucket_cnt, uint2* __restrict__ staging,
                       const float* __restrict__ X,
                       const unsigned short* __restrict__ fcwT,
                       const float* __restrict__ fcb,
                       unsigned short* __restrict__ F,
                       const float* __restrict__ Wm, unsigned short* __restrict__ WT) {
    __shared__ alignas(16) char smem[SM1_BYTES];
    int b = blockIdx.x, tid = threadIdx.x;
    if (b < P1_BLOCKS) {
        uint2* les = (uint2*)smem;                     // 32 KB
        int* cnt   = (int*)(smem + P1_CHUNK * 8);      // 196 ints
        int* woff  = cnt + NBKT;
        for (int i = tid; i < NBKT; i += 256) cnt[i] = 0;
        // per-wave dtype detect: int64 iff high dwords of first 64 ids all zero
        int v = adj[2 * (tid & 63) + 1];
        int s = (__ballot(v != 0) == 0ULL) ? 2 : 1;
        __syncthreads();
        int e0 = b * P1_CHUNK;
        int ne = N_EDGES - e0; if (ne > P1_CHUNK) ne = P1_CHUNK;
        for (int j = tid; j < ne; j += 256) {
            int e = e0 + j;
            int src, trg;
            if (s == 2) { src = adj[2 * (size_t)e]; trg = adj[2 * ((size_t)N_EDGES + e)]; }
            else        { src = adj[e];             trg = adj[N_EDGES + e]; }
            les[j] = make_uint2((unsigned)src, (unsigned)trg);
            atomicAdd(&cnt[src >> BKT_SHIFT], 1);           // LDS atomic
        }
        __syncthreads();
        for (int i = tid; i < NBKT; i += 256)
            woff[i] = atomicAdd(&bucket_cnt[i], cnt[i]);    // 196 global atomics/block
        __syncthreads();
        for (int j = tid; j < ne; j += 256) {
            uint2 et = les[j];
            int bk = (int)(et.x >> BKT_SHIFT);
            int pos = atomicAdd(&woff[bk], 1);              // LDS atomic
            if (pos < CAPB) staging[(size_t)bk * CAPB + pos] = et;
        }
        return;
    }
    b -= P1_BLOCKS;
    if (b < S1_G1_BLOCKS) {
        typedef unsigned short RowG[D_IN + G1_PAD];
        RowG* As = (RowG*)smem;
        RowG* Bs = (RowG*)(smem + 64 * (D_IN + G1_PAD) * 2);
        int lane = tid & 63, w = tid >> 6;
        int bm = b * 64;
        {   // stage A once: 4 passes x (16 rows x 128 cols), fp32 -> bf16
            int r = tid >> 4;
            int c = (tid & 15) * 8;
            #pragma unroll
            for (int p = 0; p < 4; ++p) {
                int row = r + p * 16;
                int gr = bm + row;
                unsigned short o[8] = {0, 0, 0, 0, 0, 0, 0, 0};
                if (gr < N_NODES) cvt8(X + (size_t)gr * D_IN + c, o);
                *(uint4*)(&As[row][c]) = *(const uint4*)o;
            }
        }
        int wm = (w >> 1) * 32, wn = (w & 1) * 64;
        int q = lane >> 4, l16 = lane & 15;
        for (int nc = 0; nc < 4; ++nc) {
            {   // stage B chunk: fcwT rows [nc*128, nc*128+128)
                int r = tid >> 4;
                int c = (tid & 15) * 8;
                #pragma unroll
                for (int p = 0; p < 8; ++p) {
                    int row = r + p * 16;
                    *(uint4*)(&Bs[row][c]) =
                        *(const uint4*)(fcwT + (size_t)(nc * 128 + row) * D_IN + c);
                }
            }
            __syncthreads();
            floatx4 acc[2][4] = {};
            #pragma unroll
            for (int ks = 0; ks < 4; ++ks) {
                short8 af[2], bf[4];
                #pragma unroll
                for (int mi = 0; mi < 2; ++mi)
                    af[mi] = *(const short8*)(&As[wm + mi * 16 + l16][ks * 32 + q * 8]);
                #pragma unroll
                for (int ni = 0; ni < 4; ++ni)
                    bf[ni] = *(const short8*)(&Bs[wn + ni * 16 + l16][ks * 32 + q * 8]);
                #pragma unroll
                for (int mi = 0; mi < 2; ++mi)
                    #pragma unroll
                    for (int ni = 0; ni < 4; ++ni)
                        acc[mi][ni] = __builtin_amdgcn_mfma_f32_16x16x32_bf16(af[mi], bf[ni], acc[mi][ni], 0, 0, 0);
            }
            #pragma unroll
            for (int mi = 0; mi < 2; ++mi)
                #pragma unroll
                for (int ni = 0; ni < 4; ++ni)
                    #pragma unroll
                    for (int r = 0; r < 4; ++r) {
                        int row = bm + wm + mi * 16 + q * 4 + r;
                        int col = nc * 128 + wn + ni * 16 + l16;
                        if (row < N_NODES) {
                            float v = fmaxf(acc[mi][ni][r] + fcb[col], 0.0f);
                            F[(size_t)row * D_HID + col] = f2bf(v);
                        }
                    }
            __syncthreads();   // protect Bs before next chunk restage
        }
        return;
    }
    b -= S1_G1_BLOCKS;
    {   // WT transpose (needed only by gemm2)
        int idx = b * 256 + tid;               // 640*128
        int k = idx >> 7;
        int n = idx & (D_OUT - 1);
        WT[n * CAT_DIM + k] = f2bf(Wm[idx]);
    }
}

// ================= k2: pass-2 two-pointer scatter (u16 targets) ============
// lo-half targets (trg < HALF) fill slots [0, dlo) from the front; hi-half
// fill [CAP-dhi, CAP) from the back. degp packs (dhi<<16)|dlo. Node ids fit
// u16 (N < 65536) -> halves aggregate's edge-list traffic. Overlap when
// dlo+dhi > CAP corrupts that node's tail slots -- same probability class as
// the existing CAP clamp (P ~ 1e-20), accepted.

__global__ __launch_bounds__(256)
void sort2_kernel(const int* __restrict__ bucket_cnt, const uint2* __restrict__ staging,
                  int* __restrict__ degp, unsigned short* __restrict__ el16) {
    __shared__ int lo[256], hi[256];
    int bk = blockIdx.x, tid = threadIdx.x;
    lo[tid] = 0; hi[tid] = 0;
    __syncthreads();
    int n = bucket_cnt[bk]; if (n > CAPB) n = CAPB;
    int base = bk << BKT_SHIFT;
    const uint2* st = staging + (size_t)bk * CAPB;
    for (int i = tid; i < n; i += 256) {
        uint2 et = st[i];
        int r = (int)et.x - base;
        int t = (int)et.y;
        if (t < HALF) {
            int p = atomicAdd(&lo[r], 1);
            if (p < CAP) el16[(size_t)(base + r) * CAP + p] = (unsigned short)t;
        } else {
            int p = atomicAdd(&hi[r], 1);
            if (p < CAP) el16[(size_t)(base + r) * CAP + (CAP - 1 - p)] = (unsigned short)t;
        }
    }
    __syncthreads();
    int src = base + tid;
    if (src < N_NODES) degp[src] = lo[tid] | (hi[tid] << 16);
}

// ================= aggregate v3: column-slice x XCD x trg-phase ============
// R1-R9 showed the old aggregate's 377 MB FETCH = 8 XCDs re-reading all of F
// (per-XCD working set 51.2 MB >> 4 MB L2). Fix the working set instead:
// block handles column-slice s = blockIdx%8 (64 cols = one 128B line of each
// F row); blockIdx%8 round-robins XCDs (default mapping, per T1), so XCD s
// touches only line s of F: ws = 6.4 MB. Phase-split by trg-half (separate
// launches => chip-wide phase coherence): ws = 3.2 MB < 4 MB L2 -> F fetched
// ~once (51.2 MB). Phase 1 re-reads agg (bf16-exact) and fmaxes on top.
// Wave: 8 edges in flight (sub = lane>>3), 16B chunk each (ch = lane&7);
// butterfly shfl_xor(8,16,32) reduces the 8 edge-groups. Max is partition-
// and order-invariant -> results identical. If the %8 mapping assumption is
// wrong this degrades toward the old 115 us, never below correctness.

__device__ __forceinline__ void fmax_bf16x8(float* acc, const uint4& p) {
    const unsigned* a = (const unsigned*)&p;
    #pragma unroll
    for (int j = 0; j < 4; ++j) {
        unsigned u = a[j];
        acc[2 * j]     = fmaxf(acc[2 * j],     __uint_as_float(u << 16));
        acc[2 * j + 1] = fmaxf(acc[2 * j + 1], __uint_as_float(u & 0xffff0000u));
    }
}

template<int H>
__global__ __launch_bounds__(256)
void aggregate_phase(const unsigned short* __restrict__ F,
                     const int* __restrict__ degp,
                     const unsigned short* __restrict__ el16,
                     unsigned short* __restrict__ agg) {
    int tid = threadIdx.x;
    int lane = tid & 63, w = tid >> 6;
    int s = blockIdx.x & 7;            // column slice -> XCD (default %8 map)
    int g = blockIdx.x >> 3;           // node octet
    int sub = lane >> 3;               // edge sub-slot 0..7
    int ch  = lane & 7;                // 16B chunk within the 128B line
    const unsigned short* Fs = F + s * 64 + ch * 8;
    #pragma unroll
    for (int k = 0; k < 2; ++k) {
        int n = g * 8 + w * 2 + k;     // 6250*8 blocks cover exactly 50000
        int dp = degp[n];
        int d = H ? (dp >> 16) : (dp & 0xffff);
        d = d < CAP ? d : CAP;
        float acc[8];
        if (H) {   // seed from phase-0 result (bf16 -> f32, exact)
            uint4 a0 = *(const uint4*)(agg + (size_t)n * D_HID + s * 64 + ch * 8);
            const unsigned* au = (const unsigned*)&a0;
            #pragma unroll
            for (int j = 0; j < 4; ++j) {
                acc[2 * j]     = __uint_as_float(au[j] << 16);
                acc[2 * j + 1] = __uint_as_float(au[j] & 0xffff0000u);
            }
        } else {
            #pragma unroll
            for (int j = 0; j < 8; ++j) acc[j] = 0.0f;
        }
        for (int i = 0; i < d; i += 8) {
            int e = i + sub;
            if (e < d) {
                int slot = H ? (CAP - 1 - e) : e;
                int t = el16[(size_t)n * CAP + slot];
                uint4 p = *(const uint4*)(Fs + (size_t)t * D_HID);
                fmax_bf16x8(acc, p);
            }
        }
        // butterfly max across the 8 edge sub-groups
        #pragma unroll
        for (int j = 0; j < 8; ++j) {
            acc[j] = fmaxf(acc[j], __shfl_xor(acc[j], 8, 64));
            acc[j] = fmaxf(acc[j], __shfl_xor(acc[j], 16, 64));
            acc[j] = fmaxf(acc[j], __shfl_xor(acc[j], 32, 64));
        }
        if (sub == 0) {   // lanes 0..7: write the 128B slice
            unsigned o[4];
            #pragma unroll
            for (int j = 0; j < 4; ++j) {
                unsigned lov = __float_as_uint(acc[2 * j]) >> 16;      // exact: maxima of bf16
                unsigned hiv = __float_as_uint(acc[2 * j + 1]) & 0xffff0000u;
                o[j] = lov | hiv;
            }
            *(uint4*)(agg + (size_t)n * D_HID + s * 64 + ch * 8) = *(uint4*)o;
        }
    }
}

// ================= GEMM2: A = [X fp32 | agg bf16], B = WT ==================
// BM=64, BN=128 (full D_OUT), BK=64, 10 K-steps. LDS 27648 B.

#define GPAD 8
#define GEMM_MT 782   // ceil(50000/64)

__global__ __launch_bounds__(256)
void gemm2_kernel(const float* __restrict__ X,
                  const unsigned short* __restrict__ agg,
                  const unsigned short* __restrict__ WT,
                  float* __restrict__ out) {
    __shared__ unsigned short As[64][64 + GPAD];
    __shared__ unsigned short Bs[128][64 + GPAD];
    int tid = threadIdx.x;
    int lane = tid & 63, w = tid >> 6;
    int wm = (w >> 1) * 32, wn = (w & 1) * 64;
    int q = lane >> 4, l16 = lane & 15;
    int bm = blockIdx.x * 64;
    floatx4 acc[2][4] = {};
    int ra = tid >> 2;            // A row 0..63
    int ca = (tid & 3) * 8;       // A col base; passes +0,+32
    int rb = tid >> 1;            // B row 0..127
    int cb = (tid & 1) * 8;       // B col base; passes +0,+16,+32,+48

    for (int k0 = 0; k0 < CAT_DIM; k0 += 64) {
        {
            int gr = bm + ra;
            #pragma unroll
            for (int p = 0; p < 2; ++p) {
                int col = k0 + ca + p * 32;
                unsigned short o[8] = {0, 0, 0, 0, 0, 0, 0, 0};
                if (gr < N_NODES) {
                    if (col < D_IN) cvt8(X + (size_t)gr * D_IN + col, o);
                    else *(uint4*)o = *(const uint4*)(agg + (size_t)gr * D_HID + (col - D_IN));
                }
                *(uint4*)(&As[ra][ca + p * 32]) = *(const uint4*)o;
            }
        }
        {
            const unsigned short* bp = WT + (size_t)rb * CAT_DIM + k0 + cb;
            #pragma unroll
            for (int p = 0; p < 4; ++p)
                *(uint4*)(&Bs[rb][cb + p * 16]) = *(const uint4*)(bp + p * 16);
        }
        __syncthreads();
        #pragma unroll
        for (int ks = 0; ks < 2; ++ks) {
            short8 af[2], bf[4];
            #pragma unroll
            for (int mi = 0; mi < 2; ++mi)
                af[mi] = *(const short8*)(&As[wm + mi * 16 + l16][ks * 32 + q * 8]);
            #pragma unroll
            for (int ni = 0; ni < 4; ++ni)
                bf[ni] = *(const short8*)(&Bs[wn + ni * 16 + l16][ks * 32 + q * 8]);
            #pragma unroll
            for (int mi = 0; mi < 2; ++mi)
                #pragma unroll
                for (int ni = 0; ni < 4; ++ni)
                    acc[mi][ni] = __builtin_amdgcn_mfma_f32_16x16x32_bf16(af[mi], bf[ni], acc[mi][ni], 0, 0, 0);
        }
        __syncthreads();
    }

    #pragma unroll
    for (int mi = 0; mi < 2; ++mi)
        #pragma unroll
        for (int ni = 0; ni < 4; ++ni)
            #pragma unroll
            for (int r = 0; r < 4; ++r) {
                int row = bm + wm + mi * 16 + q * 4 + r;
                int col = wn + ni * 16 + l16;
                if (row < N_NODES)
                    out[(size_t)row * D_OUT + col] = acc[mi][ni][r];
            }
}

// ================= host launch =============================================

extern "C" void kernel_launch(void* const* d_in, const int* in_sizes, int n_in,
                              void* d_out, int out_size, void* d_ws, size_t ws_size,
                              hipStream_t stream) {
    const float* X    = (const float*)d_in[0];
    const float* fc_w = (const float*)d_in[1];
    const float* fc_b = (const float*)d_in[2];
    const float* Wm   = (const float*)d_in[3];
    const int*   adj  = (const int*)d_in[4];
    float* outp = (float*)d_out;

    char* ws = (char*)d_ws;
    size_t off = 0;
    auto alloc = [&](size_t bytes) -> void* {
        void* p = ws + off;
        off = (off + bytes + 255) & ~(size_t)255;
        return p;
    };
    unsigned short* agg    = (unsigned short*)alloc((size_t)N_NODES * D_HID * 2);
    unsigned short* F      = (unsigned short*)alloc((size_t)N_NODES * D_HID * 2);
    unsigned short* fcwT   = (unsigned short*)alloc((size_t)D_HID * D_IN * 2);
    unsigned short* WT     = (unsigned short*)alloc((size_t)D_OUT * CAT_DIM * 2);
    int* degp      = (int*)alloc((size_t)N_NODES * 4);
    unsigned short* el16 = (unsigned short*)alloc((size_t)N_NODES * CAP * 2);
    int* bucket_cnt = (int*)alloc((size_t)NBKT * 4);
    uint2* staging  = (uint2*)alloc((size_t)NBKT * CAPB * 8);

    hipMemsetAsync(bucket_cnt, 0, (size_t)NBKT * 4, stream);
    prep_fcw_kernel<<<K0_BLOCKS, 256, 0, stream>>>(fc_w, fcwT);
    sort_gemm1_kernel<<<S1_BLOCKS, 256, 0, stream>>>(adj, bucket_cnt, staging,
                                                     X, fcwT, fc_b, F, Wm, WT);
    sort2_kernel<<<NBKT, 256, 0, stream>>>(bucket_cnt, staging, degp, el16);
    aggregate_phase<0><<<(N_NODES / 8) * 8, 256, 0, stream>>>(F, degp, el16, agg);
    aggregate_phase<1><<<(N_NODES / 8) * 8, 256, 0, stream>>>(F, degp, el16, agg);
    gemm2_kernel<<<GEMM_MT, 256, 0, stream>>>(X, agg, WT, outp);
}

// Round 11
// 274.195 us; speedup vs baseline: 1.5227x; 1.5227x over previous
//
#include <hip/hip_runtime.h>
#include <hip/hip_bf16.h>

#define N_NODES 50000
#define N_EDGES 800000
#define D_IN 128
#define D_HID 512
#define D_OUT 128
#define CAT_DIM 640   // D_IN + D_HID
#define CAP 64        // per-node edge-bucket capacity (Poisson(16): P(>=64) ~ 1e-20)
#define HALF 25000    // trg-phase split point

typedef __attribute__((ext_vector_type(8))) short short8;
typedef __attribute__((ext_vector_type(4))) float floatx4;

__device__ __forceinline__ unsigned short f2bf(float f) {
    unsigned u = __float_as_uint(f);
    unsigned r = u + 0x7fffu + ((u >> 16) & 1u);   // RNE
    return (unsigned short)(r >> 16);
}

// convert 8 consecutive fp32 -> 8 bf16 (same bits as a pre-cast pass)
__device__ __forceinline__ void cvt8(const float* __restrict__ src, unsigned short* o) {
    float4 v0 = *(const float4*)src;
    float4 v1 = *(const float4*)(src + 4);
    o[0] = f2bf(v0.x); o[1] = f2bf(v0.y); o[2] = f2bf(v0.z); o[3] = f2bf(v0.w);
    o[4] = f2bf(v1.x); o[5] = f2bf(v1.y); o[6] = f2bf(v1.z); o[7] = f2bf(v1.w);
}

// ================= edge binning parameters =================================

#define NBKT 196         // ceil(50000/256)
#define BKT_SHIFT 8
#define CAPB 6144        // staging capacity/bucket (mean 4082, +32 sigma)
#define P1_CHUNK 4096
#define P1_BLOCKS 196    // ceil(800000/4096)

// ================= k0: fcwT transpose (the one gemm1 dependency, ~4 us) ====

#define K0_BLOCKS 256   // 128*512 / 256

__global__ __launch_bounds__(256)
void prep_fcw_kernel(const float* __restrict__ fcW, unsigned short* __restrict__ fcwT) {
    int idx = blockIdx.x * 256 + threadIdx.x;   // 128*512
    int k = idx >> 9;
    int n = idx & (D_HID - 1);
    fcwT[n * D_IN + k] = f2bf(fcW[idx]);
}

// ================= k1: pass-1 binning ∥ GEMM1 (A-once form) ∥ WT transpose =
// (R9 form, unchanged. Front pinned ~130 us by gemm1; this round's delta is
// all in aggregate.)

#define S1_G1_BLOCKS 782    // ceil(50000/64)
#define S1_WT_BLOCKS 320    // 640*128 / 256
#define S1_BLOCKS (P1_BLOCKS + S1_G1_BLOCKS + S1_WT_BLOCKS)
#define G1_PAD 8
#define SM1_BYTES ((64 + 128) * (D_IN + G1_PAD) * 2)   // 52224

__global__ __launch_bounds__(256)
void sort_gemm1_kernel(const int* __restrict__ adj,
                       int* __restrict__ bucket_cnt, uint2* __restrict__ staging,
                       const float* __restrict__ X,
                       const unsigned short* __restrict__ fcwT,
                       const float* __restrict__ fcb,
                       unsigned short* __restrict__ F,
                       const float* __restrict__ Wm, unsigned short* __restrict__ WT) {
    __shared__ alignas(16) char smem[SM1_BYTES];
    int b = blockIdx.x, tid = threadIdx.x;
    if (b < P1_BLOCKS) {
        uint2* les = (uint2*)smem;                     // 32 KB
        int* cnt   = (int*)(smem + P1_CHUNK * 8);      // 196 ints
        int* woff  = cnt + NBKT;
        for (int i = tid; i < NBKT; i += 256) cnt[i] = 0;
        // per-wave dtype detect: int64 iff high dwords of first 64 ids all zero
        int v = adj[2 * (tid & 63) + 1];
        int s = (__ballot(v != 0) == 0ULL) ? 2 : 1;
        __syncthreads();
        int e0 = b * P1_CHUNK;
        int ne = N_EDGES - e0; if (ne > P1_CHUNK) ne = P1_CHUNK;
        for (int j = tid; j < ne; j += 256) {
            int e = e0 + j;
            int src, trg;
            if (s == 2) { src = adj[2 * (size_t)e]; trg = adj[2 * ((size_t)N_EDGES + e)]; }
            else        { src = adj[e];             trg = adj[N_EDGES + e]; }
            les[j] = make_uint2((unsigned)src, (unsigned)trg);
            atomicAdd(&cnt[src >> BKT_SHIFT], 1);           // LDS atomic
        }
        __syncthreads();
        for (int i = tid; i < NBKT; i += 256)
            woff[i] = atomicAdd(&bucket_cnt[i], cnt[i]);    // 196 global atomics/block
        __syncthreads();
        for (int j = tid; j < ne; j += 256) {
            uint2 et = les[j];
            int bk = (int)(et.x >> BKT_SHIFT);
            int pos = atomicAdd(&woff[bk], 1);              // LDS atomic
            if (pos < CAPB) staging[(size_t)bk * CAPB + pos] = et;
        }
        return;
    }
    b -= P1_BLOCKS;
    if (b < S1_G1_BLOCKS) {
        typedef unsigned short RowG[D_IN + G1_PAD];
        RowG* As = (RowG*)smem;
        RowG* Bs = (RowG*)(smem + 64 * (D_IN + G1_PAD) * 2);
        int lane = tid & 63, w = tid >> 6;
        int bm = b * 64;
        {   // stage A once: 4 passes x (16 rows x 128 cols), fp32 -> bf16
            int r = tid >> 4;
            int c = (tid & 15) * 8;
            #pragma unroll
            for (int p = 0; p < 4; ++p) {
                int row = r + p * 16;
                int gr = bm + row;
                unsigned short o[8] = {0, 0, 0, 0, 0, 0, 0, 0};
                if (gr < N_NODES) cvt8(X + (size_t)gr * D_IN + c, o);
                *(uint4*)(&As[row][c]) = *(const uint4*)o;
            }
        }
        int wm = (w >> 1) * 32, wn = (w & 1) * 64;
        int q = lane >> 4, l16 = lane & 15;
        for (int nc = 0; nc < 4; ++nc) {
            {   // stage B chunk: fcwT rows [nc*128, nc*128+128)
                int r = tid >> 4;
                int c = (tid & 15) * 8;
                #pragma unroll
                for (int p = 0; p < 8; ++p) {
                    int row = r + p * 16;
                    *(uint4*)(&Bs[row][c]) =
                        *(const uint4*)(fcwT + (size_t)(nc * 128 + row) * D_IN + c);
                }
            }
            __syncthreads();
            floatx4 acc[2][4] = {};
            #pragma unroll
            for (int ks = 0; ks < 4; ++ks) {
                short8 af[2], bf[4];
                #pragma unroll
                for (int mi = 0; mi < 2; ++mi)
                    af[mi] = *(const short8*)(&As[wm + mi * 16 + l16][ks * 32 + q * 8]);
                #pragma unroll
                for (int ni = 0; ni < 4; ++ni)
                    bf[ni] = *(const short8*)(&Bs[wn + ni * 16 + l16][ks * 32 + q * 8]);
                #pragma unroll
                for (int mi = 0; mi < 2; ++mi)
                    #pragma unroll
                    for (int ni = 0; ni < 4; ++ni)
                        acc[mi][ni] = __builtin_amdgcn_mfma_f32_16x16x32_bf16(af[mi], bf[ni], acc[mi][ni], 0, 0, 0);
            }
            #pragma unroll
            for (int mi = 0; mi < 2; ++mi)
                #pragma unroll
                for (int ni = 0; ni < 4; ++ni)
                    #pragma unroll
                    for (int r = 0; r < 4; ++r) {
                        int row = bm + wm + mi * 16 + q * 4 + r;
                        int col = nc * 128 + wn + ni * 16 + l16;
                        if (row < N_NODES) {
                            float v = fmaxf(acc[mi][ni][r] + fcb[col], 0.0f);
                            F[(size_t)row * D_HID + col] = f2bf(v);
                        }
                    }
            __syncthreads();   // protect Bs before next chunk restage
        }
        return;
    }
    b -= S1_G1_BLOCKS;
    {   // WT transpose (needed only by gemm2)
        int idx = b * 256 + tid;               // 640*128
        int k = idx >> 7;
        int n = idx & (D_OUT - 1);
        WT[n * CAT_DIM + k] = f2bf(Wm[idx]);
    }
}

// ================= k2: pass-2 two-pointer scatter (u16 targets) ============
// lo-half targets (trg < HALF) fill slots [0, dlo) from the front; hi-half
// fill [CAP-dhi, CAP) from the back. degp packs (dhi<<16)|dlo. Each phase of
// aggregate then touches ~1 line of each node's 128B row.

__global__ __launch_bounds__(256)
void sort2_kernel(const int* __restrict__ bucket_cnt, const uint2* __restrict__ staging,
                  int* __restrict__ degp, unsigned short* __restrict__ el16) {
    __shared__ int lo[256], hi[256];
    int bk = blockIdx.x, tid = threadIdx.x;
    lo[tid] = 0; hi[tid] = 0;
    __syncthreads();
    int n = bucket_cnt[bk]; if (n > CAPB) n = CAPB;
    int base = bk << BKT_SHIFT;
    const uint2* st = staging + (size_t)bk * CAPB;
    for (int i = tid; i < n; i += 256) {
        uint2 et = st[i];
        int r = (int)et.x - base;
        int t = (int)et.y;
        if (t < HALF) {
            int p = atomicAdd(&lo[r], 1);
            if (p < CAP) el16[(size_t)(base + r) * CAP + p] = (unsigned short)t;
        } else {
            int p = atomicAdd(&hi[r], 1);
            if (p < CAP) el16[(size_t)(base + r) * CAP + (CAP - 1 - p)] = (unsigned short)t;
        }
    }
    __syncthreads();
    int src = base + tid;
    if (src < N_NODES) degp[src] = lo[tid] | (hi[tid] << 16);
}

// ================= aggregate v4: group-owned node-slice, phase x XCD =======
// R10 CONFIRMED the cache mechanism (F read ~once per phase: per-XCD working
// set = half-slice 3.2 MB < 4 MB L2, via slice = blockIdx%8 -> XCD default
// round-robin) but spent ~160 us of VALU on a per-node-slice butterfly +
// 8x-duplicated per-edge overhead. v4 keeps the phase x slice scheme and
// deletes that: an 8-LANE GROUP owns one node-slice end-to-end (group =
// tid>>3 -> node, ch = tid&7 -> 16B of the 128B slice), serial fmax loop,
// NO cross-lane reduce. ~32 VGPR, no LDS -> max occupancy; unroll-2 keeps
// 2 edges in flight per group. Max is partition/order-invariant and bf16
// repack of bf16 maxima is exact -> bit-identical result.

__device__ __forceinline__ void fmax_bf16x8(float* acc, const uint4& p) {
    const unsigned* a = (const unsigned*)&p;
    #pragma unroll
    for (int j = 0; j < 4; ++j) {
        unsigned u = a[j];
        acc[2 * j]     = fmaxf(acc[2 * j],     __uint_as_float(u << 16));
        acc[2 * j + 1] = fmaxf(acc[2 * j + 1], __uint_as_float(u & 0xffff0000u));
    }
}

#define AGG_CHUNKS 1563   // ceil(50000/32)

template<int H>
__global__ __launch_bounds__(256)
void aggregate_phase(const unsigned short* __restrict__ F,
                     const int* __restrict__ degp,
                     const unsigned short* __restrict__ el16,
                     unsigned short* __restrict__ agg) {
    int tid = threadIdx.x;
    int s = blockIdx.x & 7;            // column slice -> XCD (default %8 map)
    int chunk = blockIdx.x >> 3;
    int n = chunk * 32 + (tid >> 3);   // node owned by this 8-lane group
    int ch = tid & 7;                  // 16B chunk within the 128B slice
    if (n >= N_NODES) return;
    int dp = degp[n];
    int d = H ? (dp >> 16) : (dp & 0xffff);
    d = d < CAP ? d : CAP;
    const unsigned short* Fs = F + s * 64 + ch * 8;
    const unsigned short* el = el16 + (size_t)n * CAP;
    unsigned short* ap = agg + (size_t)n * D_HID + s * 64 + ch * 8;
    float acc[8];
    if (H) {   // seed from phase-0 result (bf16 -> f32, exact)
        uint4 a0 = *(const uint4*)ap;
        const unsigned* au = (const unsigned*)&a0;
        #pragma unroll
        for (int j = 0; j < 4; ++j) {
            acc[2 * j]     = __uint_as_float(au[j] << 16);
            acc[2 * j + 1] = __uint_as_float(au[j] & 0xffff0000u);
        }
    } else {
        #pragma unroll
        for (int j = 0; j < 8; ++j) acc[j] = 0.0f;
    }
    #pragma unroll 2
    for (int i = 0; i < d; ++i) {
        int t = el[H ? (CAP - 1 - i) : i];
        uint4 p = *(const uint4*)(Fs + (size_t)t * D_HID);
        fmax_bf16x8(acc, p);
    }
    unsigned o[4];
    #pragma unroll
    for (int j = 0; j < 4; ++j) {
        unsigned lov = __float_as_uint(acc[2 * j]) >> 16;      // exact: maxima of bf16
        unsigned hiv = __float_as_uint(acc[2 * j + 1]) & 0xffff0000u;
        o[j] = lov | hiv;
    }
    *(uint4*)ap = *(uint4*)o;
}

// ================= GEMM2: A = [X fp32 | agg bf16], B = WT ==================
// BM=64, BN=128 (full D_OUT), BK=64, 10 K-steps. LDS 27648 B.

#define GPAD 8
#define GEMM_MT 782   // ceil(50000/64)

__global__ __launch_bounds__(256)
void gemm2_kernel(const float* __restrict__ X,
                  const unsigned short* __restrict__ agg,
                  const unsigned short* __restrict__ WT,
                  float* __restrict__ out) {
    __shared__ unsigned short As[64][64 + GPAD];
    __shared__ unsigned short Bs[128][64 + GPAD];
    int tid = threadIdx.x;
    int lane = tid & 63, w = tid >> 6;
    int wm = (w >> 1) * 32, wn = (w & 1) * 64;
    int q = lane >> 4, l16 = lane & 15;
    int bm = blockIdx.x * 64;
    floatx4 acc[2][4] = {};
    int ra = tid >> 2;            // A row 0..63
    int ca = (tid & 3) * 8;       // A col base; passes +0,+32
    int rb = tid >> 1;            // B row 0..127
    int cb = (tid & 1) * 8;       // B col base; passes +0,+16,+32,+48

    for (int k0 = 0; k0 < CAT_DIM; k0 += 64) {
        {
            int gr = bm + ra;
            #pragma unroll
            for (int p = 0; p < 2; ++p) {
                int col = k0 + ca + p * 32;
                unsigned short o[8] = {0, 0, 0, 0, 0, 0, 0, 0};
                if (gr < N_NODES) {
                    if (col < D_IN) cvt8(X + (size_t)gr * D_IN + col, o);
                    else *(uint4*)o = *(const uint4*)(agg + (size_t)gr * D_HID + (col - D_IN));
                }
                *(uint4*)(&As[ra][ca + p * 32]) = *(const uint4*)o;
            }
        }
        {
            const unsigned short* bp = WT + (size_t)rb * CAT_DIM + k0 + cb;
            #pragma unroll
            for (int p = 0; p < 4; ++p)
                *(uint4*)(&Bs[rb][cb + p * 16]) = *(const uint4*)(bp + p * 16);
        }
        __syncthreads();
        #pragma unroll
        for (int ks = 0; ks < 2; ++ks) {
            short8 af[2], bf[4];
            #pragma unroll
            for (int mi = 0; mi < 2; ++mi)
                af[mi] = *(const short8*)(&As[wm + mi * 16 + l16][ks * 32 + q * 8]);
            #pragma unroll
            for (int ni = 0; ni < 4; ++ni)
                bf[ni] = *(const short8*)(&Bs[wn + ni * 16 + l16][ks * 32 + q * 8]);
            #pragma unroll
            for (int mi = 0; mi < 2; ++mi)
                #pragma unroll
                for (int ni = 0; ni < 4; ++ni)
                    acc[mi][ni] = __builtin_amdgcn_mfma_f32_16x16x32_bf16(af[mi], bf[ni], acc[mi][ni], 0, 0, 0);
        }
        __syncthreads();
    }

    #pragma unroll
    for (int mi = 0; mi < 2; ++mi)
        #pragma unroll
        for (int ni = 0; ni < 4; ++ni)
            #pragma unroll
            for (int r = 0; r < 4; ++r) {
                int row = bm + wm + mi * 16 + q * 4 + r;
                int col = wn + ni * 16 + l16;
                if (row < N_NODES)
                    out[(size_t)row * D_OUT + col] = acc[mi][ni][r];
            }
}

// ================= host launch =============================================

extern "C" void kernel_launch(void* const* d_in, const int* in_sizes, int n_in,
                              void* d_out, int out_size, void* d_ws, size_t ws_size,
                              hipStream_t stream) {
    const float* X    = (const float*)d_in[0];
    const float* fc_w = (const float*)d_in[1];
    const float* fc_b = (const float*)d_in[2];
    const float* Wm   = (const float*)d_in[3];
    const int*   adj  = (const int*)d_in[4];
    float* outp = (float*)d_out;

    char* ws = (char*)d_ws;
    size_t off = 0;
    auto alloc = [&](size_t bytes) -> void* {
        void* p = ws + off;
        off = (off + bytes + 255) & ~(size_t)255;
        return p;
    };
    unsigned short* agg    = (unsigned short*)alloc((size_t)N_NODES * D_HID * 2);
    unsigned short* F      = (unsigned short*)alloc((size_t)N_NODES * D_HID * 2);
    unsigned short* fcwT   = (unsigned short*)alloc((size_t)D_HID * D_IN * 2);
    unsigned short* WT     = (unsigned short*)alloc((size_t)D_OUT * CAT_DIM * 2);
    int* degp      = (int*)alloc((size_t)N_NODES * 4);
    unsigned short* el16 = (unsigned short*)alloc((size_t)N_NODES * CAP * 2);
    int* bucket_cnt = (int*)alloc((size_t)NBKT * 4);
    uint2* staging  = (uint2*)alloc((size_t)NBKT * CAPB * 8);

    hipMemsetAsync(bucket_cnt, 0, (size_t)NBKT * 4, stream);
    prep_fcw_kernel<<<K0_BLOCKS, 256, 0, stream>>>(fc_w, fcwT);
    sort_gemm1_kernel<<<S1_BLOCKS, 256, 0, stream>>>(adj, bucket_cnt, staging,
                                                     X, fcwT, fc_b, F, Wm, WT);
    sort2_kernel<<<NBKT, 256, 0, stream>>>(bucket_cnt, staging, degp, el16);
    aggregate_phase<0><<<AGG_CHUNKS * 8, 256, 0, stream>>>(F, degp, el16, agg);
    aggregate_phase<1><<<AGG_CHUNKS * 8, 256, 0, stream>>>(F, degp, el16, agg);
    gemm2_kernel<<<GEMM_MT, 256, 0, stream>>>(X, agg, WT, outp);
}

// Round 12
// 258.980 us; speedup vs baseline: 1.6121x; 1.0587x over previous
//
#include <hip/hip_runtime.h>
#include <hip/hip_bf16.h>

#define N_NODES 50000
#define N_EDGES 800000
#define D_IN 128
#define D_HID 512
#define D_OUT 128
#define CAT_DIM 640   // D_IN + D_HID
#define CAP 64        // per-node edge-bucket capacity (Poisson(16): P(>=64) ~ 1e-20)
#define HALF 25000    // trg-phase split point

typedef __attribute__((ext_vector_type(8))) short short8;
typedef __attribute__((ext_vector_type(4))) float floatx4;

__device__ __forceinline__ unsigned short f2bf(float f) {
    unsigned u = __float_as_uint(f);
    unsigned r = u + 0x7fffu + ((u >> 16) & 1u);   // RNE
    return (unsigned short)(r >> 16);
}

// convert 8 consecutive fp32 -> 8 bf16 (same bits as a pre-cast pass)
__device__ __forceinline__ void cvt8(const float* __restrict__ src, unsigned short* o) {
    float4 v0 = *(const float4*)src;
    float4 v1 = *(const float4*)(src + 4);
    o[0] = f2bf(v0.x); o[1] = f2bf(v0.y); o[2] = f2bf(v0.z); o[3] = f2bf(v0.w);
    o[4] = f2bf(v1.x); o[5] = f2bf(v1.y); o[6] = f2bf(v1.z); o[7] = f2bf(v1.w);
}

// ================= edge binning parameters =================================

#define NBKT 196         // ceil(50000/256)
#define BKT_SHIFT 8
#define CAPB 6144        // staging capacity/bucket (mean 4082, +32 sigma)
#define P1_CHUNK 4096
#define P1_BLOCKS 196    // ceil(800000/4096)

// ================= k0: both weight transposes (off k1's critical path) =====
// R11 showed k1 at 3 blocks/CU needed ~1.7 scheduling rounds (occupancy 21%,
// long tail). WT transpose (gemm2-only input) moves here so k1's grid fits
// one round.

#define K0_FCW_BLOCKS 256   // 128*512 / 256
#define K0_WT_BLOCKS  320   // 640*128 / 256
#define K0_BLOCKS (K0_FCW_BLOCKS + K0_WT_BLOCKS)

__global__ __launch_bounds__(256)
void prep_w_kernel(const float* __restrict__ fcW, const float* __restrict__ Wm,
                   unsigned short* __restrict__ fcwT, unsigned short* __restrict__ WT) {
    int b = blockIdx.x, tid = threadIdx.x;
    if (b < K0_FCW_BLOCKS) {
        int idx = b * 256 + tid;               // 128*512
        int k = idx >> 9;
        int n = idx & (D_HID - 1);
        fcwT[n * D_IN + k] = f2bf(fcW[idx]);
        return;
    }
    b -= K0_FCW_BLOCKS;
    int idx = b * 256 + tid;                   // 640*128
    int k = idx >> 7;
    int n = idx & (D_OUT - 1);
    WT[n * CAT_DIM + k] = f2bf(Wm[idx]);
}

// ================= k1: pass-1 binning ∥ GEMM1 (A-once, Bs K-split) =========
// LDS = As[64][136] (17408 B, full K staged once: A read-once from X fp32)
//     + Bs[128][72] (18432 B, staged per (nc, k-half) from L2-resident fcwT)
//     = 35840 B -> 4 blocks/CU. Grid = 196 + 782 = 978 <= 1024 resident ->
// SINGLE scheduling round: kernel time = max(binning, gemm1 block), no tail.
// Bs staging/fragment geometry identical to gemm2's proven [128][64+8].

#define S1_G1_BLOCKS 782    // ceil(50000/64)
#define S1_BLOCKS (P1_BLOCKS + S1_G1_BLOCKS)
#define G1_PAD 8
#define SM1_BYTES (64 * (D_IN + G1_PAD) * 2 + 128 * (64 + G1_PAD) * 2)   // 35840

__global__ __launch_bounds__(256)
void sort_gemm1_kernel(const int* __restrict__ adj,
                       int* __restrict__ bucket_cnt, uint2* __restrict__ staging,
                       const float* __restrict__ X,
                       const unsigned short* __restrict__ fcwT,
                       const float* __restrict__ fcb,
                       unsigned short* __restrict__ F) {
    __shared__ alignas(16) char smem[SM1_BYTES];
    int b = blockIdx.x, tid = threadIdx.x;
    if (b < P1_BLOCKS) {
        uint2* les = (uint2*)smem;                     // 32 KB
        int* cnt   = (int*)(smem + P1_CHUNK * 8);      // 196 ints
        int* woff  = cnt + NBKT;
        for (int i = tid; i < NBKT; i += 256) cnt[i] = 0;
        // per-wave dtype detect: int64 iff high dwords of first 64 ids all zero
        int v = adj[2 * (tid & 63) + 1];
        int s = (__ballot(v != 0) == 0ULL) ? 2 : 1;
        __syncthreads();
        int e0 = b * P1_CHUNK;
        int ne = N_EDGES - e0; if (ne > P1_CHUNK) ne = P1_CHUNK;
        for (int j = tid; j < ne; j += 256) {
            int e = e0 + j;
            int src, trg;
            if (s == 2) { src = adj[2 * (size_t)e]; trg = adj[2 * ((size_t)N_EDGES + e)]; }
            else        { src = adj[e];             trg = adj[N_EDGES + e]; }
            les[j] = make_uint2((unsigned)src, (unsigned)trg);
            atomicAdd(&cnt[src >> BKT_SHIFT], 1);           // LDS atomic
        }
        __syncthreads();
        for (int i = tid; i < NBKT; i += 256)
            woff[i] = atomicAdd(&bucket_cnt[i], cnt[i]);    // 196 global atomics/block
        __syncthreads();
        for (int j = tid; j < ne; j += 256) {
            uint2 et = les[j];
            int bk = (int)(et.x >> BKT_SHIFT);
            int pos = atomicAdd(&woff[bk], 1);              // LDS atomic
            if (pos < CAPB) staging[(size_t)bk * CAPB + pos] = et;
        }
        return;
    }
    b -= P1_BLOCKS;
    {
        typedef unsigned short RowA[D_IN + G1_PAD];
        typedef unsigned short RowB[64 + G1_PAD];
        RowA* As = (RowA*)smem;
        RowB* Bs = (RowB*)(smem + 64 * (D_IN + G1_PAD) * 2);
        int lane = tid & 63, w = tid >> 6;
        int bm = b * 64;
        {   // stage A once: 4 passes x (16 rows x 128 cols), fp32 -> bf16
            int r = tid >> 4;
            int c = (tid & 15) * 8;
            #pragma unroll
            for (int p = 0; p < 4; ++p) {
                int row = r + p * 16;
                int gr = bm + row;
                unsigned short o[8] = {0, 0, 0, 0, 0, 0, 0, 0};
                if (gr < N_NODES) cvt8(X + (size_t)gr * D_IN + c, o);
                *(uint4*)(&As[row][c]) = *(const uint4*)o;
            }
        }
        int wm = (w >> 1) * 32, wn = (w & 1) * 64;
        int q = lane >> 4, l16 = lane & 15;
        int rb = tid >> 1;            // B row 0..127
        int cb = (tid & 1) * 8;       // B col base; passes +0,+16,+32,+48
        for (int nc = 0; nc < 4; ++nc) {
            floatx4 acc[2][4] = {};
            #pragma unroll
            for (int kh = 0; kh < 2; ++kh) {
                {   // stage B: fcwT rows [nc*128, +128), cols [kh*64, +64)
                    const unsigned short* bp = fcwT + (size_t)(nc * 128 + rb) * D_IN + kh * 64 + cb;
                    #pragma unroll
                    for (int p = 0; p < 4; ++p)
                        *(uint4*)(&Bs[rb][cb + p * 16]) = *(const uint4*)(bp + p * 16);
                }
                __syncthreads();
                #pragma unroll
                for (int ks = 0; ks < 2; ++ks) {
                    short8 af[2], bf[4];
                    #pragma unroll
                    for (int mi = 0; mi < 2; ++mi)
                        af[mi] = *(const short8*)(&As[wm + mi * 16 + l16][kh * 64 + ks * 32 + q * 8]);
                    #pragma unroll
                    for (int ni = 0; ni < 4; ++ni)
                        bf[ni] = *(const short8*)(&Bs[wn + ni * 16 + l16][ks * 32 + q * 8]);
                    #pragma unroll
                    for (int mi = 0; mi < 2; ++mi)
                        #pragma unroll
                        for (int ni = 0; ni < 4; ++ni)
                            acc[mi][ni] = __builtin_amdgcn_mfma_f32_16x16x32_bf16(af[mi], bf[ni], acc[mi][ni], 0, 0, 0);
                }
                __syncthreads();   // protect Bs before restage
            }
            #pragma unroll
            for (int mi = 0; mi < 2; ++mi)
                #pragma unroll
                for (int ni = 0; ni < 4; ++ni)
                    #pragma unroll
                    for (int r = 0; r < 4; ++r) {
                        int row = bm + wm + mi * 16 + q * 4 + r;
                        int col = nc * 128 + wn + ni * 16 + l16;
                        if (row < N_NODES) {
                            float v = fmaxf(acc[mi][ni][r] + fcb[col], 0.0f);
                            F[(size_t)row * D_HID + col] = f2bf(v);
                        }
                    }
        }
    }
}

// ================= k2: pass-2 two-pointer scatter (u16 targets) ============
// lo-half targets (trg < HALF) fill slots [0, dlo) from the front; hi-half
// fill [CAP-dhi, CAP) from the back. degp packs (dhi<<16)|dlo.

__global__ __launch_bounds__(256)
void sort2_kernel(const int* __restrict__ bucket_cnt, const uint2* __restrict__ staging,
                  int* __restrict__ degp, unsigned short* __restrict__ el16) {
    __shared__ int lo[256], hi[256];
    int bk = blockIdx.x, tid = threadIdx.x;
    lo[tid] = 0; hi[tid] = 0;
    __syncthreads();
    int n = bucket_cnt[bk]; if (n > CAPB) n = CAPB;
    int base = bk << BKT_SHIFT;
    const uint2* st = staging + (size_t)bk * CAPB;
    for (int i = tid; i < n; i += 256) {
        uint2 et = st[i];
        int r = (int)et.x - base;
        int t = (int)et.y;
        if (t < HALF) {
            int p = atomicAdd(&lo[r], 1);
            if (p < CAP) el16[(size_t)(base + r) * CAP + p] = (unsigned short)t;
        } else {
            int p = atomicAdd(&hi[r], 1);
            if (p < CAP) el16[(size_t)(base + r) * CAP + (CAP - 1 - p)] = (unsigned short)t;
        }
    }
    __syncthreads();
    int src = base + tid;
    if (src < N_NODES) degp[src] = lo[tid] | (hi[tid] << 16);
}

// ================= aggregate v4 (R11 form, now sub-58 us total x2) =========
// Phase x slice x XCD scheme (R10 confirmed: F read ~once/phase, per-XCD
// working set 3.2 MB < 4 MB L2 via slice = blockIdx%8 -> default XCD round-
// robin). 8-lane group owns a node-slice end-to-end: no cross-lane reduce.

__device__ __forceinline__ void fmax_bf16x8(float* acc, const uint4& p) {
    const unsigned* a = (const unsigned*)&p;
    #pragma unroll
    for (int j = 0; j < 4; ++j) {
        unsigned u = a[j];
        acc[2 * j]     = fmaxf(acc[2 * j],     __uint_as_float(u << 16));
        acc[2 * j + 1] = fmaxf(acc[2 * j + 1], __uint_as_float(u & 0xffff0000u));
    }
}

#define AGG_CHUNKS 1563   // ceil(50000/32)

template<int H>
__global__ __launch_bounds__(256)
void aggregate_phase(const unsigned short* __restrict__ F,
                     const int* __restrict__ degp,
                     const unsigned short* __restrict__ el16,
                     unsigned short* __restrict__ agg) {
    int tid = threadIdx.x;
    int s = blockIdx.x & 7;            // column slice -> XCD (default %8 map)
    int chunk = blockIdx.x >> 3;
    int n = chunk * 32 + (tid >> 3);   // node owned by this 8-lane group
    int ch = tid & 7;                  // 16B chunk within the 128B slice
    if (n >= N_NODES) return;
    int dp = degp[n];
    int d = H ? (dp >> 16) : (dp & 0xffff);
    d = d < CAP ? d : CAP;
    const unsigned short* Fs = F + s * 64 + ch * 8;
    const unsigned short* el = el16 + (size_t)n * CAP;
    unsigned short* ap = agg + (size_t)n * D_HID + s * 64 + ch * 8;
    float acc[8];
    if (H) {   // seed from phase-0 result (bf16 -> f32, exact)
        uint4 a0 = *(const uint4*)ap;
        const unsigned* au = (const unsigned*)&a0;
        #pragma unroll
        for (int j = 0; j < 4; ++j) {
            acc[2 * j]     = __uint_as_float(au[j] << 16);
            acc[2 * j + 1] = __uint_as_float(au[j] & 0xffff0000u);
        }
    } else {
        #pragma unroll
        for (int j = 0; j < 8; ++j) acc[j] = 0.0f;
    }
    #pragma unroll 2
    for (int i = 0; i < d; ++i) {
        int t = el[H ? (CAP - 1 - i) : i];
        uint4 p = *(const uint4*)(Fs + (size_t)t * D_HID);
        fmax_bf16x8(acc, p);
    }
    unsigned o[4];
    #pragma unroll
    for (int j = 0; j < 4; ++j) {
        unsigned lov = __float_as_uint(acc[2 * j]) >> 16;      // exact: maxima of bf16
        unsigned hiv = __float_as_uint(acc[2 * j + 1]) & 0xffff0000u;
        o[j] = lov | hiv;
    }
    *(uint4*)ap = *(uint4*)o;
}

// ================= GEMM2: A = [X fp32 | agg bf16], B = WT ==================
// BM=64, BN=128 (full D_OUT), BK=64, 10 K-steps. LDS 27648 B.

#define GPAD 8
#define GEMM_MT 782   // ceil(50000/64)

__global__ __launch_bounds__(256)
void gemm2_kernel(const float* __restrict__ X,
                  const unsigned short* __restrict__ agg,
                  const unsigned short* __restrict__ WT,
                  float* __restrict__ out) {
    __shared__ unsigned short As[64][64 + GPAD];
    __shared__ unsigned short Bs[128][64 + GPAD];
    int tid = threadIdx.x;
    int lane = tid & 63, w = tid >> 6;
    int wm = (w >> 1) * 32, wn = (w & 1) * 64;
    int q = lane >> 4, l16 = lane & 15;
    int bm = blockIdx.x * 64;
    floatx4 acc[2][4] = {};
    int ra = tid >> 2;            // A row 0..63
    int ca = (tid & 3) * 8;       // A col base; passes +0,+32
    int rb = tid >> 1;            // B row 0..127
    int cb = (tid & 1) * 8;       // B col base; passes +0,+16,+32,+48

    for (int k0 = 0; k0 < CAT_DIM; k0 += 64) {
        {
            int gr = bm + ra;
            #pragma unroll
            for (int p = 0; p < 2; ++p) {
                int col = k0 + ca + p * 32;
                unsigned short o[8] = {0, 0, 0, 0, 0, 0, 0, 0};
                if (gr < N_NODES) {
                    if (col < D_IN) cvt8(X + (size_t)gr * D_IN + col, o);
                    else *(uint4*)o = *(const uint4*)(agg + (size_t)gr * D_HID + (col - D_IN));
                }
                *(uint4*)(&As[ra][ca + p * 32]) = *(const uint4*)o;
            }
        }
        {
            const unsigned short* bp = WT + (size_t)rb * CAT_DIM + k0 + cb;
            #pragma unroll
            for (int p = 0; p < 4; ++p)
                *(uint4*)(&Bs[rb][cb + p * 16]) = *(const uint4*)(bp + p * 16);
        }
        __syncthreads();
        #pragma unroll
        for (int ks = 0; ks < 2; ++ks) {
            short8 af[2], bf[4];
            #pragma unroll
            for (int mi = 0; mi < 2; ++mi)
                af[mi] = *(const short8*)(&As[wm + mi * 16 + l16][ks * 32 + q * 8]);
            #pragma unroll
            for (int ni = 0; ni < 4; ++ni)
                bf[ni] = *(const short8*)(&Bs[wn + ni * 16 + l16][ks * 32 + q * 8]);
            #pragma unroll
            for (int mi = 0; mi < 2; ++mi)
                #pragma unroll
                for (int ni = 0; ni < 4; ++ni)
                    acc[mi][ni] = __builtin_amdgcn_mfma_f32_16x16x32_bf16(af[mi], bf[ni], acc[mi][ni], 0, 0, 0);
        }
        __syncthreads();
    }

    #pragma unroll
    for (int mi = 0; mi < 2; ++mi)
        #pragma unroll
        for (int ni = 0; ni < 4; ++ni)
            #pragma unroll
            for (int r = 0; r < 4; ++r) {
                int row = bm + wm + mi * 16 + q * 4 + r;
                int col = wn + ni * 16 + l16;
                if (row < N_NODES)
                    out[(size_t)row * D_OUT + col] = acc[mi][ni][r];
            }
}

// ================= host launch =============================================

extern "C" void kernel_launch(void* const* d_in, const int* in_sizes, int n_in,
                              void* d_out, int out_size, void* d_ws, size_t ws_size,
                              hipStream_t stream) {
    const float* X    = (const float*)d_in[0];
    const float* fc_w = (const float*)d_in[1];
    const float* fc_b = (const float*)d_in[2];
    const float* Wm   = (const float*)d_in[3];
    const int*   adj  = (const int*)d_in[4];
    float* outp = (float*)d_out;

    char* ws = (char*)d_ws;
    size_t off = 0;
    auto alloc = [&](size_t bytes) -> void* {
        void* p = ws + off;
        off = (off + bytes + 255) & ~(size_t)255;
        return p;
    };
    unsigned short* agg    = (unsigned short*)alloc((size_t)N_NODES * D_HID * 2);
    unsigned short* F      = (unsigned short*)alloc((size_t)N_NODES * D_HID * 2);
    unsigned short* fcwT   = (unsigned short*)alloc((size_t)D_HID * D_IN * 2);
    unsigned short* WT     = (unsigned short*)alloc((size_t)D_OUT * CAT_DIM * 2);
    int* degp      = (int*)alloc((size_t)N_NODES * 4);
    unsigned short* el16 = (unsigned short*)alloc((size_t)N_NODES * CAP * 2);
    int* bucket_cnt = (int*)alloc((size_t)NBKT * 4);
    uint2* staging  = (uint2*)alloc((size_t)NBKT * CAPB * 8);

    hipMemsetAsync(bucket_cnt, 0, (size_t)NBKT * 4, stream);
    prep_w_kernel<<<K0_BLOCKS, 256, 0, stream>>>(fc_w, Wm, fcwT, WT);
    sort_gemm1_kernel<<<S1_BLOCKS, 256, 0, stream>>>(adj, bucket_cnt, staging,
                                                     X, fcwT, fc_b, F);
    sort2_kernel<<<NBKT, 256, 0, stream>>>(bucket_cnt, staging, degp, el16);
    aggregate_phase<0><<<AGG_CHUNKS * 8, 256, 0, stream>>>(F, degp, el16, agg);
    aggregate_phase<1><<<AGG_CHUNKS * 8, 256, 0, stream>>>(F, degp, el16, agg);
    gemm2_kernel<<<GEMM_MT, 256, 0, stream>>>(X, agg, WT, outp);
}

// Round 13
// 250.431 us; speedup vs baseline: 1.6672x; 1.0341x over previous
//
#include <hip/hip_runtime.h>
#include <hip/hip_bf16.h>

#define N_NODES 50000
#define N_EDGES 800000
#define D_IN 128
#define D_HID 512
#define D_OUT 128
#define CAT_DIM 640   // D_IN + D_HID
#define CAP 64        // legacy per-node capacity (staging margins sized off this)
#define CAPH 32       // per-half capacity (Poisson(8): P(>32) ~ 3e-11)
#define HALF 25000    // trg-phase split point

typedef __attribute__((ext_vector_type(8))) short short8;
typedef __attribute__((ext_vector_type(4))) float floatx4;

__device__ __forceinline__ unsigned short f2bf(float f) {
    unsigned u = __float_as_uint(f);
    unsigned r = u + 0x7fffu + ((u >> 16) & 1u);   // RNE
    return (unsigned short)(r >> 16);
}

// convert 8 consecutive fp32 -> 8 bf16 (same bits as a pre-cast pass)
__device__ __forceinline__ void cvt8(const float* __restrict__ src, unsigned short* o) {
    float4 v0 = *(const float4*)src;
    float4 v1 = *(const float4*)(src + 4);
    o[0] = f2bf(v0.x); o[1] = f2bf(v0.y); o[2] = f2bf(v0.z); o[3] = f2bf(v0.w);
    o[4] = f2bf(v1.x); o[5] = f2bf(v1.y); o[6] = f2bf(v1.z); o[7] = f2bf(v1.w);
}

// ================= edge binning parameters =================================

#define NBKT 196         // ceil(50000/256)
#define BKT_SHIFT 8
#define CAPB 6144        // staging capacity/bucket (mean 4082, +32 sigma)
#define P1_CHUNK 4096
#define P1_BLOCKS 196    // ceil(800000/4096)

// ================= k0: weight transposes + bucket_cnt zero =================
// (memset folded in: one fewer dispatch; R12 showed ~50 us of inter-dispatch
// gaps across 7 dispatches.)

#define K0_FCW_BLOCKS 256   // 128*512 / 256
#define K0_WT_BLOCKS  320   // 640*128 / 256
#define K0_BLOCKS (K0_FCW_BLOCKS + K0_WT_BLOCKS + 1)

__global__ __launch_bounds__(256)
void prep_w_kernel(const float* __restrict__ fcW, const float* __restrict__ Wm,
                   unsigned short* __restrict__ fcwT, unsigned short* __restrict__ WT,
                   int* __restrict__ bucket_cnt) {
    int b = blockIdx.x, tid = threadIdx.x;
    if (b < K0_FCW_BLOCKS) {
        int idx = b * 256 + tid;               // 128*512
        int k = idx >> 9;
        int n = idx & (D_HID - 1);
        fcwT[n * D_IN + k] = f2bf(fcW[idx]);
        return;
    }
    b -= K0_FCW_BLOCKS;
    if (b < K0_WT_BLOCKS) {
        int idx = b * 256 + tid;               // 640*128
        int k = idx >> 7;
        int n = idx & (D_OUT - 1);
        WT[n * CAT_DIM + k] = f2bf(Wm[idx]);
        return;
    }
    if (tid < NBKT) bucket_cnt[tid] = 0;
}

// ================= k1: pass-1 binning ∥ GEMM1 (A-once, Bs K-split) =========
// R12 form (258.98 us): LDS 35840 B -> 4 blocks/CU; grid 978 <= 1024
// resident -> single scheduling round. Do not touch.

#define S1_G1_BLOCKS 782    // ceil(50000/64)
#define S1_BLOCKS (P1_BLOCKS + S1_G1_BLOCKS)
#define G1_PAD 8
#define SM1_BYTES (64 * (D_IN + G1_PAD) * 2 + 128 * (64 + G1_PAD) * 2)   // 35840

__global__ __launch_bounds__(256)
void sort_gemm1_kernel(const int* __restrict__ adj,
                       int* __restrict__ bucket_cnt, uint2* __restrict__ staging,
                       const float* __restrict__ X,
                       const unsigned short* __restrict__ fcwT,
                       const float* __restrict__ fcb,
                       unsigned short* __restrict__ F) {
    __shared__ alignas(16) char smem[SM1_BYTES];
    int b = blockIdx.x, tid = threadIdx.x;
    if (b < P1_BLOCKS) {
        uint2* les = (uint2*)smem;                     // 32 KB
        int* cnt   = (int*)(smem + P1_CHUNK * 8);      // 196 ints
        int* woff  = cnt + NBKT;
        for (int i = tid; i < NBKT; i += 256) cnt[i] = 0;
        // per-wave dtype detect: int64 iff high dwords of first 64 ids all zero
        int v = adj[2 * (tid & 63) + 1];
        int s = (__ballot(v != 0) == 0ULL) ? 2 : 1;
        __syncthreads();
        int e0 = b * P1_CHUNK;
        int ne = N_EDGES - e0; if (ne > P1_CHUNK) ne = P1_CHUNK;
        for (int j = tid; j < ne; j += 256) {
            int e = e0 + j;
            int src, trg;
            if (s == 2) { src = adj[2 * (size_t)e]; trg = adj[2 * ((size_t)N_EDGES + e)]; }
            else        { src = adj[e];             trg = adj[N_EDGES + e]; }
            les[j] = make_uint2((unsigned)src, (unsigned)trg);
            atomicAdd(&cnt[src >> BKT_SHIFT], 1);           // LDS atomic
        }
        __syncthreads();
        for (int i = tid; i < NBKT; i += 256)
            woff[i] = atomicAdd(&bucket_cnt[i], cnt[i]);    // 196 global atomics/block
        __syncthreads();
        for (int j = tid; j < ne; j += 256) {
            uint2 et = les[j];
            int bk = (int)(et.x >> BKT_SHIFT);
            int pos = atomicAdd(&woff[bk], 1);              // LDS atomic
            if (pos < CAPB) staging[(size_t)bk * CAPB + pos] = et;
        }
        return;
    }
    b -= P1_BLOCKS;
    {
        typedef unsigned short RowA[D_IN + G1_PAD];
        typedef unsigned short RowB[64 + G1_PAD];
        RowA* As = (RowA*)smem;
        RowB* Bs = (RowB*)(smem + 64 * (D_IN + G1_PAD) * 2);
        int lane = tid & 63, w = tid >> 6;
        int bm = b * 64;
        {   // stage A once: 4 passes x (16 rows x 128 cols), fp32 -> bf16
            int r = tid >> 4;
            int c = (tid & 15) * 8;
            #pragma unroll
            for (int p = 0; p < 4; ++p) {
                int row = r + p * 16;
                int gr = bm + row;
                unsigned short o[8] = {0, 0, 0, 0, 0, 0, 0, 0};
                if (gr < N_NODES) cvt8(X + (size_t)gr * D_IN + c, o);
                *(uint4*)(&As[row][c]) = *(const uint4*)o;
            }
        }
        int wm = (w >> 1) * 32, wn = (w & 1) * 64;
        int q = lane >> 4, l16 = lane & 15;
        int rb = tid >> 1;            // B row 0..127
        int cb = (tid & 1) * 8;       // B col base; passes +0,+16,+32,+48
        for (int nc = 0; nc < 4; ++nc) {
            floatx4 acc[2][4] = {};
            #pragma unroll
            for (int kh = 0; kh < 2; ++kh) {
                {   // stage B: fcwT rows [nc*128, +128), cols [kh*64, +64)
                    const unsigned short* bp = fcwT + (size_t)(nc * 128 + rb) * D_IN + kh * 64 + cb;
                    #pragma unroll
                    for (int p = 0; p < 4; ++p)
                        *(uint4*)(&Bs[rb][cb + p * 16]) = *(const uint4*)(bp + p * 16);
                }
                __syncthreads();
                #pragma unroll
                for (int ks = 0; ks < 2; ++ks) {
                    short8 af[2], bf[4];
                    #pragma unroll
                    for (int mi = 0; mi < 2; ++mi)
                        af[mi] = *(const short8*)(&As[wm + mi * 16 + l16][kh * 64 + ks * 32 + q * 8]);
                    #pragma unroll
                    for (int ni = 0; ni < 4; ++ni)
                        bf[ni] = *(const short8*)(&Bs[wn + ni * 16 + l16][ks * 32 + q * 8]);
                    #pragma unroll
                    for (int mi = 0; mi < 2; ++mi)
                        #pragma unroll
                        for (int ni = 0; ni < 4; ++ni)
                            acc[mi][ni] = __builtin_amdgcn_mfma_f32_16x16x32_bf16(af[mi], bf[ni], acc[mi][ni], 0, 0, 0);
                }
                __syncthreads();   // protect Bs before restage
            }
            #pragma unroll
            for (int mi = 0; mi < 2; ++mi)
                #pragma unroll
                for (int ni = 0; ni < 4; ++ni)
                    #pragma unroll
                    for (int r = 0; r < 4; ++r) {
                        int row = bm + wm + mi * 16 + q * 4 + r;
                        int col = nc * 128 + wn + ni * 16 + l16;
                        if (row < N_NODES) {
                            float v = fmaxf(acc[mi][ni][r] + fcb[col], 0.0f);
                            F[(size_t)row * D_HID + col] = f2bf(v);
                        }
                    }
        }
    }
}

// ================= k2: pass-2 scatter into phase-split el arrays ===========
// elLo/elHi are SEPARATE [50000][32] u16 arrays (64 B/node each) so each
// aggregate phase fetches only its own lines: per-phase el traffic 51.2 ->
// 25.6 MB (R12 counters showed the shared-line layout pulled the full 128 B
// line in both phases). Forward writes, per-half clamp at 32.

__global__ __launch_bounds__(256)
void sort2_kernel(const int* __restrict__ bucket_cnt, const uint2* __restrict__ staging,
                  int* __restrict__ degp,
                  unsigned short* __restrict__ elLo, unsigned short* __restrict__ elHi) {
    __shared__ int lo[256], hi[256];
    int bk = blockIdx.x, tid = threadIdx.x;
    lo[tid] = 0; hi[tid] = 0;
    __syncthreads();
    int n = bucket_cnt[bk]; if (n > CAPB) n = CAPB;
    int base = bk << BKT_SHIFT;
    const uint2* st = staging + (size_t)bk * CAPB;
    for (int i = tid; i < n; i += 256) {
        uint2 et = st[i];
        int r = (int)et.x - base;
        int t = (int)et.y;
        if (t < HALF) {
            int p = atomicAdd(&lo[r], 1);
            if (p < CAPH) elLo[(size_t)(base + r) * CAPH + p] = (unsigned short)t;
        } else {
            int p = atomicAdd(&hi[r], 1);
            if (p < CAPH) elHi[(size_t)(base + r) * CAPH + p] = (unsigned short)t;
        }
    }
    __syncthreads();
    int src = base + tid;
    if (src < N_NODES) degp[src] = lo[tid] | (hi[tid] << 16);
}

// ================= aggregate: phase x slice x XCD (R11/R12 core) ===========
// F read ~once per phase: per-XCD working set = half-slice 3.2 MB < 4 MB L2
// via slice = blockIdx%8 -> default XCD round-robin. 8-lane group owns a
// node-slice end-to-end (no cross-lane reduce). Phase arrays are line-
// exclusive now (elLo/elHi).

__device__ __forceinline__ void fmax_bf16x8(float* acc, const uint4& p) {
    const unsigned* a = (const unsigned*)&p;
    #pragma unroll
    for (int j = 0; j < 4; ++j) {
        unsigned u = a[j];
        acc[2 * j]     = fmaxf(acc[2 * j],     __uint_as_float(u << 16));
        acc[2 * j + 1] = fmaxf(acc[2 * j + 1], __uint_as_float(u & 0xffff0000u));
    }
}

#define AGG_CHUNKS 1563   // ceil(50000/32)

template<int H>
__global__ __launch_bounds__(256)
void aggregate_phase(const unsigned short* __restrict__ F,
                     const int* __restrict__ degp,
                     const unsigned short* __restrict__ el,
                     unsigned short* __restrict__ agg) {
    int tid = threadIdx.x;
    int s = blockIdx.x & 7;            // column slice -> XCD (default %8 map)
    int chunk = blockIdx.x >> 3;
    int n = chunk * 32 + (tid >> 3);   // node owned by this 8-lane group
    int ch = tid & 7;                  // 16B chunk within the 128B slice
    if (n >= N_NODES) return;
    int dp = degp[n];
    int d = H ? (dp >> 16) : (dp & 0xffff);
    d = d < CAPH ? d : CAPH;
    const unsigned short* Fs = F + s * 64 + ch * 8;
    const unsigned short* ep = el + (size_t)n * CAPH;
    unsigned short* ap = agg + (size_t)n * D_HID + s * 64 + ch * 8;
    float acc[8];
    if (H) {   // seed from phase-0 result (bf16 -> f32, exact)
        uint4 a0 = *(const uint4*)ap;
        const unsigned* au = (const unsigned*)&a0;
        #pragma unroll
        for (int j = 0; j < 4; ++j) {
            acc[2 * j]     = __uint_as_float(au[j] << 16);
            acc[2 * j + 1] = __uint_as_float(au[j] & 0xffff0000u);
        }
    } else {
        #pragma unroll
        for (int j = 0; j < 8; ++j) acc[j] = 0.0f;
    }
    #pragma unroll 2
    for (int i = 0; i < d; ++i) {
        int t = ep[i];
        uint4 p = *(const uint4*)(Fs + (size_t)t * D_HID);
        fmax_bf16x8(acc, p);
    }
    unsigned o[4];
    #pragma unroll
    for (int j = 0; j < 4; ++j) {
        unsigned lov = __float_as_uint(acc[2 * j]) >> 16;      // exact: maxima of bf16
        unsigned hiv = __float_as_uint(acc[2 * j + 1]) & 0xffff0000u;
        o[j] = lov | hiv;
    }
    *(uint4*)ap = *(uint4*)o;
}

// ================= GEMM2: A = [X fp32 | agg bf16], B = WT ==================
// BM=64, BN=128 (full D_OUT), BK=64, 10 K-steps. LDS 27648 B.

#define GPAD 8
#define GEMM_MT 782   // ceil(50000/64)

__global__ __launch_bounds__(256)
void gemm2_kernel(const float* __restrict__ X,
                  const unsigned short* __restrict__ agg,
                  const unsigned short* __restrict__ WT,
                  float* __restrict__ out) {
    __shared__ unsigned short As[64][64 + GPAD];
    __shared__ unsigned short Bs[128][64 + GPAD];
    int tid = threadIdx.x;
    int lane = tid & 63, w = tid >> 6;
    int wm = (w >> 1) * 32, wn = (w & 1) * 64;
    int q = lane >> 4, l16 = lane & 15;
    int bm = blockIdx.x * 64;
    floatx4 acc[2][4] = {};
    int ra = tid >> 2;            // A row 0..63
    int ca = (tid & 3) * 8;       // A col base; passes +0,+32
    int rb = tid >> 1;            // B row 0..127
    int cb = (tid & 1) * 8;       // B col base; passes +0,+16,+32,+48

    for (int k0 = 0; k0 < CAT_DIM; k0 += 64) {
        {
            int gr = bm + ra;
            #pragma unroll
            for (int p = 0; p < 2; ++p) {
                int col = k0 + ca + p * 32;
                unsigned short o[8] = {0, 0, 0, 0, 0, 0, 0, 0};
                if (gr < N_NODES) {
                    if (col < D_IN) cvt8(X + (size_t)gr * D_IN + col, o);
                    else *(uint4*)o = *(const uint4*)(agg + (size_t)gr * D_HID + (col - D_IN));
                }
                *(uint4*)(&As[ra][ca + p * 32]) = *(const uint4*)o;
            }
        }
        {
            const unsigned short* bp = WT + (size_t)rb * CAT_DIM + k0 + cb;
            #pragma unroll
            for (int p = 0; p < 4; ++p)
                *(uint4*)(&Bs[rb][cb + p * 16]) = *(const uint4*)(bp + p * 16);
        }
        __syncthreads();
        #pragma unroll
        for (int ks = 0; ks < 2; ++ks) {
            short8 af[2], bf[4];
            #pragma unroll
            for (int mi = 0; mi < 2; ++mi)
                af[mi] = *(const short8*)(&As[wm + mi * 16 + l16][ks * 32 + q * 8]);
            #pragma unroll
            for (int ni = 0; ni < 4; ++ni)
                bf[ni] = *(const short8*)(&Bs[wn + ni * 16 + l16][ks * 32 + q * 8]);
            #pragma unroll
            for (int mi = 0; mi < 2; ++mi)
                #pragma unroll
                for (int ni = 0; ni < 4; ++ni)
                    acc[mi][ni] = __builtin_amdgcn_mfma_f32_16x16x32_bf16(af[mi], bf[ni], acc[mi][ni], 0, 0, 0);
        }
        __syncthreads();
    }

    #pragma unroll
    for (int mi = 0; mi < 2; ++mi)
        #pragma unroll
        for (int ni = 0; ni < 4; ++ni)
            #pragma unroll
            for (int r = 0; r < 4; ++r) {
                int row = bm + wm + mi * 16 + q * 4 + r;
                int col = wn + ni * 16 + l16;
                if (row < N_NODES)
                    out[(size_t)row * D_OUT + col] = acc[mi][ni][r];
            }
}

// ================= host launch =============================================

extern "C" void kernel_launch(void* const* d_in, const int* in_sizes, int n_in,
                              void* d_out, int out_size, void* d_ws, size_t ws_size,
                              hipStream_t stream) {
    const float* X    = (const float*)d_in[0];
    const float* fc_w = (const float*)d_in[1];
    const float* fc_b = (const float*)d_in[2];
    const float* Wm   = (const float*)d_in[3];
    const int*   adj  = (const int*)d_in[4];
    float* outp = (float*)d_out;

    char* ws = (char*)d_ws;
    size_t off = 0;
    auto alloc = [&](size_t bytes) -> void* {
        void* p = ws + off;
        off = (off + bytes + 255) & ~(size_t)255;
        return p;
    };
    unsigned short* agg    = (unsigned short*)alloc((size_t)N_NODES * D_HID * 2);
    unsigned short* F      = (unsigned short*)alloc((size_t)N_NODES * D_HID * 2);
    unsigned short* fcwT   = (unsigned short*)alloc((size_t)D_HID * D_IN * 2);
    unsigned short* WT     = (unsigned short*)alloc((size_t)D_OUT * CAT_DIM * 2);
    int* degp      = (int*)alloc((size_t)N_NODES * 4);
    unsigned short* elLo = (unsigned short*)alloc((size_t)N_NODES * CAPH * 2);
    unsigned short* elHi = (unsigned short*)alloc((size_t)N_NODES * CAPH * 2);
    int* bucket_cnt = (int*)alloc((size_t)NBKT * 4);
    uint2* staging  = (uint2*)alloc((size_t)NBKT * CAPB * 8);

    prep_w_kernel<<<K0_BLOCKS, 256, 0, stream>>>(fc_w, Wm, fcwT, WT, bucket_cnt);
    sort_gemm1_kernel<<<S1_BLOCKS, 256, 0, stream>>>(adj, bucket_cnt, staging,
                                                     X, fcwT, fc_b, F);
    sort2_kernel<<<NBKT, 256, 0, stream>>>(bucket_cnt, staging, degp, elLo, elHi);
    aggregate_phase<0><<<AGG_CHUNKS * 8, 256, 0, stream>>>(F, degp, elLo, agg);
    aggregate_phase<1><<<AGG_CHUNKS * 8, 256, 0, stream>>>(F, degp, elHi, agg);
    gemm2_kernel<<<GEMM_MT, 256, 0, stream>>>(X, agg, WT, outp);
}